// Round 4
// baseline (992.713 us; speedup 1.0000x reference)
//
#include <hip/hip_runtime.h>
#include <hip/hip_bf16.h>

#define N_NODES 50000
#define N_REL   4
#define N_EDGES 500000
#define EMB     128
#define HID     128
#define OUTD    64
#define NC      8            // atomic-spread replicas

// ---- 1) degree counting into NC replicated counters (blockIdx&7 -> copy) ---
__global__ void count_kernel(const int* __restrict__ src, const int* __restrict__ dst,
                             int* __restrict__ cnt_out, int* __restrict__ cnt_in) {
    int e = blockIdx.x * blockDim.x + threadIdx.x;
    int r = blockIdx.y;
    if (e >= N_EDGES) return;
    int c = blockIdx.x & (NC - 1);
    size_t base = ((size_t)c * N_REL + r) * N_NODES;
    atomicAdd(&cnt_out[base + src[(size_t)r * N_EDGES + e]], 1);
    atomicAdd(&cnt_in [base + dst[(size_t)r * N_EDGES + e]], 1);
}

// ---- 2) reduce copies -> totals, norms --------------------------------------
__global__ void reduce_kernel(const int* __restrict__ cnt_out, const int* __restrict__ cnt_in,
                              int* __restrict__ deg_in_tot,
                              float* __restrict__ nsrc, float* __restrict__ ndst) {
    int i = blockIdx.x * blockDim.x + threadIdx.x;
    if (i >= N_REL * N_NODES) return;
    int so = 0, si = 0;
#pragma unroll
    for (int c = 0; c < NC; ++c) {
        so += cnt_out[(size_t)c * N_REL * N_NODES + i];
        si += cnt_in [(size_t)c * N_REL * N_NODES + i];
    }
    deg_in_tot[i] = si;
    nsrc[i] = so > 0 ? rsqrtf((float)so) : 0.0f;
    ndst[i] = si > 0 ? rsqrtf((float)si) : 0.0f;
}

// ---- 3) exclusive scan of deg_in_tot -> offs (one block per relation) -------
__global__ __launch_bounds__(1024) void scan_kernel(const int* __restrict__ deg_in,
                                                    int* __restrict__ offs) {
    __shared__ int sh[1024];
    const int r = blockIdx.x;
    const int t = threadIdx.x;
    const int CH = 49;                          // 49*1024 >= 50001
    const int start = t * CH;
    int sum = 0;
    for (int j = start; j < start + CH; ++j)
        if (j < N_NODES) sum += deg_in[r * N_NODES + j];
    sh[t] = sum;
    __syncthreads();
    for (int off = 1; off < 1024; off <<= 1) {
        int v = (t >= off) ? sh[t - off] : 0;
        __syncthreads();
        sh[t] += v;
        __syncthreads();
    }
    int run = sh[t] - sum;
    for (int j = start; j < start + CH; ++j) {
        if (j <= N_NODES) {
            offs[r * (N_NODES + 1) + j] = run;
            if (j < N_NODES) run += deg_in[r * N_NODES + j];
        }
    }
}

// ---- 4) per-copy cursors ----------------------------------------------------
__global__ void cursor_kernel(const int* __restrict__ cnt_in, const int* __restrict__ offs,
                              int* __restrict__ cursor) {
    int i = blockIdx.x * blockDim.x + threadIdx.x;
    if (i >= N_REL * N_NODES) return;
    int r = i / N_NODES, n = i - r * N_NODES;
    int run = offs[r * (N_NODES + 1) + n];
#pragma unroll
    for (int c = 0; c < NC; ++c) {
        cursor[(size_t)c * N_REL * N_NODES + i] = run;
        run += cnt_in[(size_t)c * N_REL * N_NODES + i];
    }
}

// ---- 5) place edges: csr_rec = {src, nsrc[src]} sorted by dst ---------------
__global__ void place_kernel(const int* __restrict__ src, const int* __restrict__ dst,
                             const float* __restrict__ nsrc,
                             int* __restrict__ cursor, int2* __restrict__ csr_rec) {
    int e = blockIdx.x * blockDim.x + threadIdx.x;
    int r = blockIdx.y;
    if (e >= N_EDGES) return;
    int c = blockIdx.x & (NC - 1);
    int s = src[(size_t)r * N_EDGES + e];
    int d = dst[(size_t)r * N_EDGES + e];
    int p = atomicAdd(&cursor[((size_t)c * N_REL + r) * N_NODES + d], 1);
    csr_rec[(size_t)r * N_EDGES + p] = make_int2(s, __float_as_int(nsrc[(size_t)r * N_NODES + s]));
}

// ---- 6) gather1: one wave per dst node, all 4 relations interleaved ---------
// agg[wid][r*128 + :] = 0.25 * nd_r[d] * sum_{e in r} x[src_e] * ns_r[src_e]
__global__ __launch_bounds__(256) void gather1_kernel(
    const float* __restrict__ x,              // [N][128]
    const int2* __restrict__ csr_rec,         // [R][E]
    const int* __restrict__ offs,             // [R][N+1]
    const float* __restrict__ ndst,           // [R][N]
    float* __restrict__ agg,                  // [chunk][512]
    int node0, int nnodes) {
    int wid = (blockIdx.x * 256 + threadIdx.x) >> 6;
    int lane = threadIdx.x & 63;
    if (wid >= nnodes) return;
    int d = node0 + wid;
    const float2* x2 = (const float2*)x;      // row = 64 float2
    float ax[N_REL], ay[N_REL];
    int e[N_REL], e1[N_REL];
#pragma unroll
    for (int r = 0; r < N_REL; ++r) {
        ax[r] = 0.0f; ay[r] = 0.0f;
        e[r] = offs[r * (N_NODES + 1) + d];
        e1[r] = offs[r * (N_NODES + 1) + d + 1];
    }
    for (;;) {
        bool go[N_REL];
        bool any = false;
#pragma unroll
        for (int r = 0; r < N_REL; ++r) {
            go[r] = (e[r] + 1 < e1[r]);
            any = any || go[r];
        }
        if (!any) break;
        int2 rc0[N_REL], rc1[N_REL];
#pragma unroll
        for (int r = 0; r < N_REL; ++r)
            if (go[r]) {
                rc0[r] = csr_rec[(size_t)r * N_EDGES + e[r]];
                rc1[r] = csr_rec[(size_t)r * N_EDGES + e[r] + 1];
            }
        float2 v0[N_REL], v1[N_REL];
#pragma unroll
        for (int r = 0; r < N_REL; ++r)
            if (go[r]) {
                v0[r] = x2[(size_t)rc0[r].x * 64 + lane];
                v1[r] = x2[(size_t)rc1[r].x * 64 + lane];
            }
#pragma unroll
        for (int r = 0; r < N_REL; ++r)
            if (go[r]) {
                float w0 = __int_as_float(rc0[r].y), w1 = __int_as_float(rc1[r].y);
                ax[r] += v0[r].x * w0 + v1[r].x * w1;
                ay[r] += v0[r].y * w0 + v1[r].y * w1;
                e[r] += 2;
            }
    }
#pragma unroll
    for (int r = 0; r < N_REL; ++r) {
        if (e[r] < e1[r]) {                   // odd tail
            int2 rc = csr_rec[(size_t)r * N_EDGES + e[r]];
            float w = __int_as_float(rc.y);
            float2 v = x2[(size_t)rc.x * 64 + lane];
            ax[r] += v.x * w;
            ay[r] += v.y * w;
        }
    }
    float2* arow = (float2*)(agg + (size_t)wid * (N_REL * EMB));
#pragma unroll
    for (int r = 0; r < N_REL; ++r) {
        float sc = 0.25f * ndst[(size_t)r * N_NODES + d];
        float2 o;
        o.x = ax[r] * sc;
        o.y = ay[r] * sc;
        arow[r * 64 + lane] = o;
    }
}

// ---- 7) gemm_h1: h1[n][128] = agg[n][512] @ W1flat + 0.25*sum_r b1_r --------
__global__ __launch_bounds__(256) void gemm_h1(
    const float* __restrict__ agg, const float* __restrict__ W,   // [512][128]
    const float* __restrict__ b1,                                 // [4][128]
    float* __restrict__ h1, int node0, int nnodes) {
    constexpr int K = 512, HO = 128, KT = 32, NJ = 4;
    __shared__ float xt[64][36];
    __shared__ float wtT[HO][36];
    const int t = threadIdx.x, tc = t & 31, tr = t >> 5;
    const int row0 = blockIdx.x * 64;
    float acc[8][NJ] = {};
    for (int k0 = 0; k0 < K; k0 += KT) {
#pragma unroll
        for (int q = 0; q < 2; ++q) {         // X tile: 512 float4
            int idx = t + q * 256;
            int row = idx >> 3, c4 = idx & 7;
            float4 v = {};
            if (row0 + row < nnodes)
                v = *(const float4*)&agg[(size_t)(row0 + row) * K + k0 + c4 * 4];
            *(float4*)&xt[row][c4 * 4] = v;
        }
#pragma unroll
        for (int q = 0; q < 4; ++q) {         // W tile transposed: 1024 float4
            int idx = t + q * 256;
            int k = idx >> 5, c4 = (idx & 31) * 4;
            float4 v = *(const float4*)&W[(size_t)(k0 + k) * HO + c4];
            wtT[c4 + 0][k] = v.x;
            wtT[c4 + 1][k] = v.y;
            wtT[c4 + 2][k] = v.z;
            wtT[c4 + 3][k] = v.w;
        }
        __syncthreads();
#pragma unroll
        for (int kk = 0; kk < KT; kk += 4) {
            float4 xv[8], wv[NJ];
#pragma unroll
            for (int i = 0; i < 8; ++i) xv[i] = *(const float4*)&xt[tr + 8 * i][kk];
#pragma unroll
            for (int j = 0; j < NJ; ++j) wv[j] = *(const float4*)&wtT[tc + 32 * j][kk];
#pragma unroll
            for (int i = 0; i < 8; ++i)
#pragma unroll
                for (int j = 0; j < NJ; ++j)
                    acc[i][j] += xv[i].x * wv[j].x + xv[i].y * wv[j].y
                               + xv[i].z * wv[j].z + xv[i].w * wv[j].w;
        }
        __syncthreads();
    }
#pragma unroll
    for (int i = 0; i < 8; ++i) {
        int row = row0 + tr + 8 * i;
        if (row < nnodes) {
#pragma unroll
            for (int j = 0; j < NJ; ++j) {
                int c = tc + 32 * j;
                float bv = 0.25f * (b1[c] + b1[HO + c] + b1[2 * HO + c] + b1[3 * HO + c]);
                h1[(size_t)(node0 + row) * HO + c] = acc[i][j] + bv;
            }
        }
    }
}

// ---- 8) gemm_proj: p2[n][r*64+c] = ns_r[n] * (h1[n] @ W2_r)[c] --------------
__global__ __launch_bounds__(256) void gemm_proj(
    const float* __restrict__ h1,             // [N][128]
    const float* __restrict__ W2,             // [4][128][64]
    const float* __restrict__ nsrc,           // [4][N]
    float* __restrict__ p2) {                 // [N][256]
    constexpr int K = 128, HO = 256, KT = 32, NJ = 8;
    __shared__ float xt[64][36];
    __shared__ float wtT[HO][36];
    const int t = threadIdx.x, tc = t & 31, tr = t >> 5;
    const int row0 = blockIdx.x * 64;
    float acc[8][NJ] = {};
    for (int k0 = 0; k0 < K; k0 += KT) {
#pragma unroll
        for (int q = 0; q < 2; ++q) {         // X tile
            int idx = t + q * 256;
            int row = idx >> 3, c4 = idx & 7;
            float4 v = {};
            if (row0 + row < N_NODES)
                v = *(const float4*)&h1[(size_t)(row0 + row) * K + k0 + c4 * 4];
            *(float4*)&xt[row][c4 * 4] = v;
        }
#pragma unroll
        for (int q = 0; q < 8; ++q) {         // W2cat tile transposed: 2048 float4
            int idx = t + q * 256;
            int k = idx >> 6, c4 = (idx & 63) * 4;
            int r = c4 >> 6, cc = c4 & 63;
            float4 v = *(const float4*)&W2[((size_t)r * K + k0 + k) * 64 + cc];
            wtT[c4 + 0][k] = v.x;
            wtT[c4 + 1][k] = v.y;
            wtT[c4 + 2][k] = v.z;
            wtT[c4 + 3][k] = v.w;
        }
        __syncthreads();
#pragma unroll
        for (int kk = 0; kk < KT; kk += 4) {
            float4 xv[8], wv[NJ];
#pragma unroll
            for (int i = 0; i < 8; ++i) xv[i] = *(const float4*)&xt[tr + 8 * i][kk];
#pragma unroll
            for (int j = 0; j < NJ; ++j) wv[j] = *(const float4*)&wtT[tc + 32 * j][kk];
#pragma unroll
            for (int i = 0; i < 8; ++i)
#pragma unroll
                for (int j = 0; j < NJ; ++j)
                    acc[i][j] += xv[i].x * wv[j].x + xv[i].y * wv[j].y
                               + xv[i].z * wv[j].z + xv[i].w * wv[j].w;
        }
        __syncthreads();
    }
#pragma unroll
    for (int i = 0; i < 8; ++i) {
        int row = row0 + tr + 8 * i;
        if (row < N_NODES) {
            float nsq[N_REL];
#pragma unroll
            for (int r = 0; r < N_REL; ++r) nsq[r] = nsrc[(size_t)r * N_NODES + row];
#pragma unroll
            for (int j = 0; j < NJ; ++j) {
                int c = tc + 32 * j;
                p2[(size_t)row * HO + c] = acc[i][j] * nsq[c >> 6];
            }
        }
    }
}

// ---- 9) gather2: out[d][c] = 0.25*sum_r nd_r[d]*sum_e p2[s][r*64+c] + bias --
__global__ __launch_bounds__(256) void gather2_kernel(
    const float* __restrict__ p2,             // [N][256]
    const int2* __restrict__ csr_rec,
    const int* __restrict__ offs,
    const float* __restrict__ ndst,
    const float* __restrict__ b2,             // [4][64]
    float* __restrict__ out) {
    int wid = (blockIdx.x * 256 + threadIdx.x) >> 6;
    int lane = threadIdx.x & 63;
    if (wid >= N_NODES) return;
    int d = wid;
    float a[N_REL] = {0.f, 0.f, 0.f, 0.f};
    int e[N_REL], e1[N_REL];
#pragma unroll
    for (int r = 0; r < N_REL; ++r) {
        e[r] = offs[r * (N_NODES + 1) + d];
        e1[r] = offs[r * (N_NODES + 1) + d + 1];
    }
    for (;;) {
        bool go[N_REL];
        bool any = false;
#pragma unroll
        for (int r = 0; r < N_REL; ++r) {
            go[r] = (e[r] + 1 < e1[r]);
            any = any || go[r];
        }
        if (!any) break;
        int2 rc0[N_REL], rc1[N_REL];
#pragma unroll
        for (int r = 0; r < N_REL; ++r)
            if (go[r]) {
                rc0[r] = csr_rec[(size_t)r * N_EDGES + e[r]];
                rc1[r] = csr_rec[(size_t)r * N_EDGES + e[r] + 1];
            }
        float v0[N_REL], v1[N_REL];
#pragma unroll
        for (int r = 0; r < N_REL; ++r)
            if (go[r]) {
                v0[r] = p2[(size_t)rc0[r].x * 256 + r * 64 + lane];
                v1[r] = p2[(size_t)rc1[r].x * 256 + r * 64 + lane];
            }
#pragma unroll
        for (int r = 0; r < N_REL; ++r)
            if (go[r]) {
                a[r] += v0[r] + v1[r];
                e[r] += 2;
            }
    }
#pragma unroll
    for (int r = 0; r < N_REL; ++r)
        if (e[r] < e1[r]) {
            int2 rc = csr_rec[(size_t)r * N_EDGES + e[r]];
            a[r] += p2[(size_t)rc.x * 256 + r * 64 + lane];
        }
    float res = 0.0f;
#pragma unroll
    for (int r = 0; r < N_REL; ++r) res += a[r] * ndst[(size_t)r * N_NODES + d];
    res = 0.25f * res + 0.25f * (b2[lane] + b2[64 + lane] + b2[128 + lane] + b2[192 + lane]);
    out[(size_t)d * OUTD + lane] = res;
}

// ----------------------------------------------------------------- launch ---
extern "C" void kernel_launch(void* const* d_in, const int* in_sizes, int n_in,
                              void* d_out, int out_size, void* d_ws, size_t ws_size,
                              hipStream_t stream) {
    const int* src = (const int*)d_in[1];
    const int* dst = (const int*)d_in[2];
    const float* emb = (const float*)d_in[3];
    const float* W1 = (const float*)d_in[4];
    const float* b1 = (const float*)d_in[5];
    const float* W2 = (const float*)d_in[6];
    const float* b2 = (const float*)d_in[7];
    float* out = (float*)d_out;

    char* p = (char*)d_ws;
    auto alloc = [&](size_t bytes) -> void* {
        void* q = (void*)p;
        p += (bytes + 255) & ~(size_t)255;
        return q;
    };
    int* cnt_out = (int*)alloc((size_t)NC * N_REL * N_NODES * 4);   // 6.4 MB
    int* cnt_in  = (int*)alloc((size_t)NC * N_REL * N_NODES * 4);   // 6.4 MB
    int* deg_in_tot = (int*)alloc((size_t)N_REL * N_NODES * 4);
    int* offs = (int*)alloc((size_t)N_REL * (N_NODES + 1) * 4);
    int* cursor = (int*)alloc((size_t)NC * N_REL * N_NODES * 4);    // 6.4 MB
    int2* csr_rec = (int2*)alloc((size_t)N_REL * N_EDGES * 8);      // 16 MB
    float* nsrc = (float*)alloc((size_t)N_REL * N_NODES * 4);
    float* ndst = (float*)alloc((size_t)N_REL * N_NODES * 4);
    float* h1 = (float*)alloc((size_t)N_NODES * HID * 4);           // 25.6 MB
    float* p2 = (float*)alloc((size_t)N_NODES * 256 * 4);           // 51.2 MB
    size_t used = (size_t)(p - (char*)d_ws);
    size_t avail = ws_size > used ? ws_size - used : 0;
    size_t maxn = avail / (512 * 4);
    int npc = (int)(maxn > (size_t)N_NODES ? (size_t)N_NODES : maxn);
    if (npc < 256) npc = 256;
    float* agg = (float*)p;

    hipMemsetAsync(cnt_out, 0, (size_t)2 * NC * N_REL * N_NODES * 4, stream);
    dim3 egrid((N_EDGES + 255) / 256, N_REL);
    count_kernel<<<egrid, 256, 0, stream>>>(src, dst, cnt_out, cnt_in);
    reduce_kernel<<<(N_REL * N_NODES + 255) / 256, 256, 0, stream>>>(
        cnt_out, cnt_in, deg_in_tot, nsrc, ndst);
    scan_kernel<<<N_REL, 1024, 0, stream>>>(deg_in_tot, offs);
    cursor_kernel<<<(N_REL * N_NODES + 255) / 256, 256, 0, stream>>>(cnt_in, offs, cursor);
    place_kernel<<<egrid, 256, 0, stream>>>(src, dst, nsrc, cursor, csr_rec);

    // layer 1: emb -> agg(chunked) -> h1
    for (int n0 = 0; n0 < N_NODES; n0 += npc) {
        int nn = (N_NODES - n0) < npc ? (N_NODES - n0) : npc;
        gather1_kernel<<<(nn + 3) / 4, 256, 0, stream>>>(emb, csr_rec, offs, ndst, agg, n0, nn);
        gemm_h1<<<(nn + 63) / 64, 256, 0, stream>>>(agg, W1, b1, h1, n0, nn);
    }
    // layer 2: h1 -> p2 (project-first, all relations) -> out
    gemm_proj<<<(N_NODES + 63) / 64, 256, 0, stream>>>(h1, W2, nsrc, p2);
    gather2_kernel<<<(N_NODES * 64 + 255) / 256, 256, 0, stream>>>(
        p2, csr_rec, offs, ndst, b2, out);
}

// Round 5
// 853.861 us; speedup vs baseline: 1.1626x; 1.1626x over previous
//
#include <hip/hip_runtime.h>
#include <hip/hip_bf16.h>

#define N_NODES 50000
#define N_REL   4
#define N_EDGES 500000
#define EMB     128
#define HID     128
#define OUTD    64
#define NC      8            // atomic-spread replicas

// ---- 1) degree counting into NC replicated counters (blockIdx&7 -> copy) ---
__global__ void count_kernel(const int* __restrict__ src, const int* __restrict__ dst,
                             int* __restrict__ cnt_out, int* __restrict__ cnt_in) {
    int e = blockIdx.x * blockDim.x + threadIdx.x;
    int r = blockIdx.y;
    if (e >= N_EDGES) return;
    int c = blockIdx.x & (NC - 1);
    size_t base = ((size_t)c * N_REL + r) * N_NODES;
    atomicAdd(&cnt_out[base + src[(size_t)r * N_EDGES + e]], 1);
    atomicAdd(&cnt_in [base + dst[(size_t)r * N_EDGES + e]], 1);
}

// ---- 2) reduce copies -> totals, norms --------------------------------------
__global__ void reduce_kernel(const int* __restrict__ cnt_out, const int* __restrict__ cnt_in,
                              int* __restrict__ deg_in_tot,
                              float* __restrict__ nsrc, float* __restrict__ ndst) {
    int i = blockIdx.x * blockDim.x + threadIdx.x;
    if (i >= N_REL * N_NODES) return;
    int so = 0, si = 0;
#pragma unroll
    for (int c = 0; c < NC; ++c) {
        so += cnt_out[(size_t)c * N_REL * N_NODES + i];
        si += cnt_in [(size_t)c * N_REL * N_NODES + i];
    }
    deg_in_tot[i] = si;
    nsrc[i] = so > 0 ? rsqrtf((float)so) : 0.0f;
    ndst[i] = si > 0 ? rsqrtf((float)si) : 0.0f;
}

// ---- 3) exclusive scan of deg_in_tot -> offs (one block per relation) -------
__global__ __launch_bounds__(1024) void scan_kernel(const int* __restrict__ deg_in,
                                                    int* __restrict__ offs) {
    __shared__ int sh[1024];
    const int r = blockIdx.x;
    const int t = threadIdx.x;
    const int CH = 49;                          // 49*1024 >= 50001
    const int start = t * CH;
    int sum = 0;
    for (int j = start; j < start + CH; ++j)
        if (j < N_NODES) sum += deg_in[r * N_NODES + j];
    sh[t] = sum;
    __syncthreads();
    for (int off = 1; off < 1024; off <<= 1) {
        int v = (t >= off) ? sh[t - off] : 0;
        __syncthreads();
        sh[t] += v;
        __syncthreads();
    }
    int run = sh[t] - sum;
    for (int j = start; j < start + CH; ++j) {
        if (j <= N_NODES) {
            offs[r * (N_NODES + 1) + j] = run;
            if (j < N_NODES) run += deg_in[r * N_NODES + j];
        }
    }
}

// ---- 4) per-copy cursors ----------------------------------------------------
__global__ void cursor_kernel(const int* __restrict__ cnt_in, const int* __restrict__ offs,
                              int* __restrict__ cursor) {
    int i = blockIdx.x * blockDim.x + threadIdx.x;
    if (i >= N_REL * N_NODES) return;
    int r = i / N_NODES, n = i - r * N_NODES;
    int run = offs[r * (N_NODES + 1) + n];
#pragma unroll
    for (int c = 0; c < NC; ++c) {
        cursor[(size_t)c * N_REL * N_NODES + i] = run;
        run += cnt_in[(size_t)c * N_REL * N_NODES + i];
    }
}

// ---- 5) place edges: csr_rec = {src, nsrc[src]} sorted by dst ---------------
__global__ void place_kernel(const int* __restrict__ src, const int* __restrict__ dst,
                             const float* __restrict__ nsrc,
                             int* __restrict__ cursor, int2* __restrict__ csr_rec) {
    int e = blockIdx.x * blockDim.x + threadIdx.x;
    int r = blockIdx.y;
    if (e >= N_EDGES) return;
    int c = blockIdx.x & (NC - 1);
    int s = src[(size_t)r * N_EDGES + e];
    int d = dst[(size_t)r * N_EDGES + e];
    int p = atomicAdd(&cursor[((size_t)c * N_REL + r) * N_NODES + d], 1);
    csr_rec[(size_t)r * N_EDGES + p] = make_int2(s, __float_as_int(nsrc[(size_t)r * N_NODES + s]));
}

// ---- 6) gather1: one wave per dst node, all 4 relations interleaved ---------
__global__ __launch_bounds__(256) void gather1_kernel(
    const float* __restrict__ x,              // [N][128]
    const int2* __restrict__ csr_rec,         // [R][E]
    const int* __restrict__ offs,             // [R][N+1]
    const float* __restrict__ ndst,           // [R][N]
    float* __restrict__ agg,                  // [chunk][512]
    int node0, int nnodes) {
    int wid = (blockIdx.x * 256 + threadIdx.x) >> 6;
    int lane = threadIdx.x & 63;
    if (wid >= nnodes) return;
    int d = node0 + wid;
    const float2* x2 = (const float2*)x;      // row = 64 float2
    float ax[N_REL], ay[N_REL];
    int e[N_REL], e1[N_REL];
#pragma unroll
    for (int r = 0; r < N_REL; ++r) {
        ax[r] = 0.0f; ay[r] = 0.0f;
        e[r] = offs[r * (N_NODES + 1) + d];
        e1[r] = offs[r * (N_NODES + 1) + d + 1];
    }
    for (;;) {
        bool go[N_REL];
        bool any = false;
#pragma unroll
        for (int r = 0; r < N_REL; ++r) {
            go[r] = (e[r] + 1 < e1[r]);
            any = any || go[r];
        }
        if (!any) break;
        int2 rc0[N_REL], rc1[N_REL];
#pragma unroll
        for (int r = 0; r < N_REL; ++r)
            if (go[r]) {
                rc0[r] = csr_rec[(size_t)r * N_EDGES + e[r]];
                rc1[r] = csr_rec[(size_t)r * N_EDGES + e[r] + 1];
            }
        float2 v0[N_REL], v1[N_REL];
#pragma unroll
        for (int r = 0; r < N_REL; ++r)
            if (go[r]) {
                v0[r] = x2[(size_t)rc0[r].x * 64 + lane];
                v1[r] = x2[(size_t)rc1[r].x * 64 + lane];
            }
#pragma unroll
        for (int r = 0; r < N_REL; ++r)
            if (go[r]) {
                float w0 = __int_as_float(rc0[r].y), w1 = __int_as_float(rc1[r].y);
                ax[r] += v0[r].x * w0 + v1[r].x * w1;
                ay[r] += v0[r].y * w0 + v1[r].y * w1;
                e[r] += 2;
            }
    }
#pragma unroll
    for (int r = 0; r < N_REL; ++r) {
        if (e[r] < e1[r]) {                   // odd tail
            int2 rc = csr_rec[(size_t)r * N_EDGES + e[r]];
            float w = __int_as_float(rc.y);
            float2 v = x2[(size_t)rc.x * 64 + lane];
            ax[r] += v.x * w;
            ay[r] += v.y * w;
        }
    }
    float2* arow = (float2*)(agg + (size_t)wid * (N_REL * EMB));
#pragma unroll
    for (int r = 0; r < N_REL; ++r) {
        float sc = 0.25f * ndst[(size_t)r * N_NODES + d];
        float2 o;
        o.x = ax[r] * sc;
        o.y = ay[r] * sc;
        arow[r * 64 + lane] = o;
    }
}

// ---- 7) gemm1: h1[n][128] = agg[n][512] @ W1flat + 0.25*sum_r b1_r ----------
// 64x128 block tile, 256 threads, 4x8 thread tile, conflict-free scalar reads.
__global__ __launch_bounds__(256) void gemm1_kernel(
    const float* __restrict__ agg, const float* __restrict__ W,   // [512][128]
    const float* __restrict__ b1,                                 // [4][128]
    float* __restrict__ h1, int node0, int nnodes) {
    constexpr int K = 512, HO = 128, KT = 32;
    __shared__ float xt[64][33];
    __shared__ float wt[KT][HO];
    const int t = threadIdx.x;
    const int tx = t & 15, ty = t >> 4;         // 16x16 thread grid
    const int row0 = blockIdx.x * 64;
    float acc[4][8] = {};
    for (int k0 = 0; k0 < K; k0 += KT) {
#pragma unroll
        for (int q = 0; q < 2; ++q) {           // X tile: 512 float4
            int idx = t + q * 256;
            int row = idx >> 3, c4 = idx & 7;
            float4 v = {};
            if (row0 + row < nnodes)
                v = *(const float4*)&agg[(size_t)(row0 + row) * K + k0 + c4 * 4];
            xt[row][c4 * 4 + 0] = v.x;
            xt[row][c4 * 4 + 1] = v.y;
            xt[row][c4 * 4 + 2] = v.z;
            xt[row][c4 * 4 + 3] = v.w;
        }
#pragma unroll
        for (int q = 0; q < 4; ++q) {           // W tile: 1024 float4
            int idx = t + q * 256;
            int k = idx >> 5, c4 = idx & 31;
            *(float4*)&wt[k][c4 * 4] = *(const float4*)&W[(size_t)(k0 + k) * HO + c4 * 4];
        }
        __syncthreads();
#pragma unroll
        for (int kk = 0; kk < KT; ++kk) {
            float xv[4], wv[8];
#pragma unroll
            for (int i = 0; i < 4; ++i) xv[i] = xt[ty + 16 * i][kk];
#pragma unroll
            for (int j = 0; j < 8; ++j) wv[j] = wt[kk][tx + 16 * j];
#pragma unroll
            for (int i = 0; i < 4; ++i)
#pragma unroll
                for (int j = 0; j < 8; ++j) acc[i][j] += xv[i] * wv[j];
        }
        __syncthreads();
    }
#pragma unroll
    for (int j = 0; j < 8; ++j) {
        int c = tx + 16 * j;
        float bv = 0.25f * (b1[c] + b1[HO + c] + b1[2 * HO + c] + b1[3 * HO + c]);
#pragma unroll
        for (int i = 0; i < 4; ++i) {
            int row = row0 + ty + 16 * i;
            if (row < nnodes)
                h1[(size_t)(node0 + row) * HO + c] = acc[i][j] + bv;
        }
    }
}

// ---- 8) gemm2: p2[n][cb*128+c] = ns_{r(c)}[n] * (h1[n] @ W2cat)[c] ----------
// grid.y = column block (2 x 128 cols). Same tile structure as gemm1.
__global__ __launch_bounds__(256) void gemm2_kernel(
    const float* __restrict__ h1,             // [N][128]
    const float* __restrict__ W2,             // [4][128][64]
    const float* __restrict__ nsrc,           // [4][N]
    float* __restrict__ p2) {                 // [N][256]
    constexpr int K = 128, KT = 32;
    __shared__ float xt[64][33];
    __shared__ float wt[KT][128];
    const int t = threadIdx.x;
    const int tx = t & 15, ty = t >> 4;
    const int row0 = blockIdx.x * 64;
    const int cb = blockIdx.y;                  // 0 or 1
    float acc[4][8] = {};
    for (int k0 = 0; k0 < K; k0 += KT) {
#pragma unroll
        for (int q = 0; q < 2; ++q) {           // X tile
            int idx = t + q * 256;
            int row = idx >> 3, c4 = idx & 7;
            float4 v = {};
            if (row0 + row < N_NODES)
                v = *(const float4*)&h1[(size_t)(row0 + row) * K + k0 + c4 * 4];
            xt[row][c4 * 4 + 0] = v.x;
            xt[row][c4 * 4 + 1] = v.y;
            xt[row][c4 * 4 + 2] = v.z;
            xt[row][c4 * 4 + 3] = v.w;
        }
#pragma unroll
        for (int q = 0; q < 4; ++q) {           // W tile: cols cb*128..+127
            int idx = t + q * 256;
            int k = idx >> 5, c4 = idx & 31;
            int r = cb * 2 + (c4 >> 4);         // global col = cb*128 + c4*4
            int col = (c4 * 4) & 63;
            *(float4*)&wt[k][c4 * 4] =
                *(const float4*)&W2[((size_t)r * K + k0 + k) * 64 + col];
        }
        __syncthreads();
#pragma unroll
        for (int kk = 0; kk < KT; ++kk) {
            float xv[4], wv[8];
#pragma unroll
            for (int i = 0; i < 4; ++i) xv[i] = xt[ty + 16 * i][kk];
#pragma unroll
            for (int j = 0; j < 8; ++j) wv[j] = wt[kk][tx + 16 * j];
#pragma unroll
            for (int i = 0; i < 4; ++i)
#pragma unroll
                for (int j = 0; j < 8; ++j) acc[i][j] += xv[i] * wv[j];
        }
        __syncthreads();
    }
#pragma unroll
    for (int i = 0; i < 4; ++i) {
        int row = row0 + ty + 16 * i;
        if (row < N_NODES) {
            float ns0 = nsrc[(size_t)(cb * 2 + 0) * N_NODES + row];
            float ns1 = nsrc[(size_t)(cb * 2 + 1) * N_NODES + row];
#pragma unroll
            for (int j = 0; j < 8; ++j) {
                int c = tx + 16 * j;            // 0..127 within block
                float s = (c < 64) ? ns0 : ns1;
                p2[(size_t)row * 256 + cb * 128 + c] = acc[i][j] * s;
            }
        }
    }
}

// ---- 9) gather2: out[d][c] = 0.25*sum_r nd_r[d]*sum_e p2[s][r*64+c] + bias --
__global__ __launch_bounds__(256) void gather2_kernel(
    const float* __restrict__ p2,             // [N][256]
    const int2* __restrict__ csr_rec,
    const int* __restrict__ offs,
    const float* __restrict__ ndst,
    const float* __restrict__ b2,             // [4][64]
    float* __restrict__ out) {
    int wid = (blockIdx.x * 256 + threadIdx.x) >> 6;
    int lane = threadIdx.x & 63;
    if (wid >= N_NODES) return;
    int d = wid;
    float a[N_REL] = {0.f, 0.f, 0.f, 0.f};
    int e[N_REL], e1[N_REL];
#pragma unroll
    for (int r = 0; r < N_REL; ++r) {
        e[r] = offs[r * (N_NODES + 1) + d];
        e1[r] = offs[r * (N_NODES + 1) + d + 1];
    }
    for (;;) {
        bool go[N_REL];
        bool any = false;
#pragma unroll
        for (int r = 0; r < N_REL; ++r) {
            go[r] = (e[r] + 1 < e1[r]);
            any = any || go[r];
        }
        if (!any) break;
        int2 rc0[N_REL], rc1[N_REL];
#pragma unroll
        for (int r = 0; r < N_REL; ++r)
            if (go[r]) {
                rc0[r] = csr_rec[(size_t)r * N_EDGES + e[r]];
                rc1[r] = csr_rec[(size_t)r * N_EDGES + e[r] + 1];
            }
        float v0[N_REL], v1[N_REL];
#pragma unroll
        for (int r = 0; r < N_REL; ++r)
            if (go[r]) {
                v0[r] = p2[(size_t)rc0[r].x * 256 + r * 64 + lane];
                v1[r] = p2[(size_t)rc1[r].x * 256 + r * 64 + lane];
            }
#pragma unroll
        for (int r = 0; r < N_REL; ++r)
            if (go[r]) {
                a[r] += v0[r] + v1[r];
                e[r] += 2;
            }
    }
#pragma unroll
    for (int r = 0; r < N_REL; ++r)
        if (e[r] < e1[r]) {
            int2 rc = csr_rec[(size_t)r * N_EDGES + e[r]];
            a[r] += p2[(size_t)rc.x * 256 + r * 64 + lane];
        }
    float res = 0.0f;
#pragma unroll
    for (int r = 0; r < N_REL; ++r) res += a[r] * ndst[(size_t)r * N_NODES + d];
    res = 0.25f * res + 0.25f * (b2[lane] + b2[64 + lane] + b2[128 + lane] + b2[192 + lane]);
    out[(size_t)d * OUTD + lane] = res;
}

// ----------------------------------------------------------------- launch ---
extern "C" void kernel_launch(void* const* d_in, const int* in_sizes, int n_in,
                              void* d_out, int out_size, void* d_ws, size_t ws_size,
                              hipStream_t stream) {
    const int* src = (const int*)d_in[1];
    const int* dst = (const int*)d_in[2];
    const float* emb = (const float*)d_in[3];
    const float* W1 = (const float*)d_in[4];
    const float* b1 = (const float*)d_in[5];
    const float* W2 = (const float*)d_in[6];
    const float* b2 = (const float*)d_in[7];
    float* out = (float*)d_out;

    char* p = (char*)d_ws;
    auto alloc = [&](size_t bytes) -> void* {
        void* q = (void*)p;
        p += (bytes + 255) & ~(size_t)255;
        return q;
    };
    int* cnt_out = (int*)alloc((size_t)NC * N_REL * N_NODES * 4);   // 6.4 MB
    int* cnt_in  = (int*)alloc((size_t)NC * N_REL * N_NODES * 4);   // 6.4 MB
    int* deg_in_tot = (int*)alloc((size_t)N_REL * N_NODES * 4);
    int* offs = (int*)alloc((size_t)N_REL * (N_NODES + 1) * 4);
    int* cursor = (int*)alloc((size_t)NC * N_REL * N_NODES * 4);    // 6.4 MB
    int2* csr_rec = (int2*)alloc((size_t)N_REL * N_EDGES * 8);      // 16 MB
    float* nsrc = (float*)alloc((size_t)N_REL * N_NODES * 4);
    float* ndst = (float*)alloc((size_t)N_REL * N_NODES * 4);
    float* h1 = (float*)alloc((size_t)N_NODES * HID * 4);           // 25.6 MB
    float* p2 = (float*)alloc((size_t)N_NODES * 256 * 4);           // 51.2 MB
    size_t used = (size_t)(p - (char*)d_ws);
    size_t avail = ws_size > used ? ws_size - used : 0;
    size_t maxn = avail / (512 * 4);
    int npc = (int)(maxn > (size_t)N_NODES ? (size_t)N_NODES : maxn);
    if (npc < 256) npc = 256;
    float* agg = (float*)p;

    hipMemsetAsync(cnt_out, 0, (size_t)2 * NC * N_REL * N_NODES * 4, stream);
    dim3 egrid((N_EDGES + 255) / 256, N_REL);
    count_kernel<<<egrid, 256, 0, stream>>>(src, dst, cnt_out, cnt_in);
    reduce_kernel<<<(N_REL * N_NODES + 255) / 256, 256, 0, stream>>>(
        cnt_out, cnt_in, deg_in_tot, nsrc, ndst);
    scan_kernel<<<N_REL, 1024, 0, stream>>>(deg_in_tot, offs);
    cursor_kernel<<<(N_REL * N_NODES + 255) / 256, 256, 0, stream>>>(cnt_in, offs, cursor);
    place_kernel<<<egrid, 256, 0, stream>>>(src, dst, nsrc, cursor, csr_rec);

    // layer 1: emb -> agg(chunked) -> h1
    for (int n0 = 0; n0 < N_NODES; n0 += npc) {
        int nn = (N_NODES - n0) < npc ? (N_NODES - n0) : npc;
        gather1_kernel<<<(nn + 3) / 4, 256, 0, stream>>>(emb, csr_rec, offs, ndst, agg, n0, nn);
        gemm1_kernel<<<(nn + 63) / 64, 256, 0, stream>>>(agg, W1, b1, h1, n0, nn);
    }
    // layer 2: h1 -> p2 (project-first, all relations) -> out
    dim3 g2grid((N_NODES + 63) / 64, 2);
    gemm2_kernel<<<g2grid, 256, 0, stream>>>(h1, W2, nsrc, p2);
    gather2_kernel<<<(N_NODES * 64 + 255) / 256, 256, 0, stream>>>(
        p2, csr_rec, offs, ndst, b2, out);
}